// Round 13
// baseline (785.165 us; speedup 1.0000x reference)
//
#include <hip/hip_runtime.h>
#include <hip/hip_bf16.h>
#include <stdint.h>

#define Bq  8
#define Sq  2048
#define Dq  768
#define Hq  3072
#define Oq  768
#define Eq  8
#define Mq  (Bq*Sq)            // 16384 tokens
#define LN_EPS 1e-5f
#define MAX_TILES (2*Mq/128 + 16)   // 272 worst-case padded 128-row tiles

typedef unsigned short u16;
typedef __attribute__((ext_vector_type(4))) float f32x4;
typedef __attribute__((ext_vector_type(8))) __bf16 bf16x8;

static __device__ __forceinline__ u16 f2bf(float f) {
  __hip_bfloat16 h = __float2bfloat16(f);
  return __builtin_bit_cast(u16, h);
}

static __device__ __forceinline__ float gelu_f(float x) {
  // jax.nn.gelu approximate=True (tanh form)
  float u = 0.7978845608028654f * x * (1.0f + 0.044715f * x * x);
  float e = __expf(2.0f * u);
  float t = 1.0f - 2.0f / (e + 1.0f);   // tanh(u), NaN-free
  return 0.5f * x * (1.0f + t);
}

typedef const __attribute__((address_space(1))) void* gas_t;
typedef __attribute__((address_space(3))) void* las_t;
static __device__ __forceinline__ void gload16(const void* g, void* l) {
  __builtin_amdgcn_global_load_lds((gas_t)g, (las_t)l, 16, 0, 0);
}

// ---------------- fused router + fp32->bf16 convert. NO atomics.
__global__ __launch_bounds__(256) void router_cvt_kernel(
    const float* __restrict__ x, const float* __restrict__ rw,
    const float* __restrict__ rb, u16* __restrict__ Xbf,
    int* __restrict__ tok_seg, float2* __restrict__ tok_w)
{
  __shared__ float rwT[Eq * Dq];      // 24 KB: rwT[e][d]
  for (int i = threadIdx.x; i < Eq * Dq; i += 256)
    rwT[(i & 7) * Dq + (i >> 3)] = rw[i];
  __syncthreads();

  int wid = threadIdx.x >> 6;
  int lane = threadIdx.x & 63;
  int token = blockIdx.x * 4 + wid;
  const float4* xrow = (const float4*)(x + (size_t)token * Dq);
  ushort4* orow = (ushort4*)(Xbf + (size_t)token * Dq);

  float acc[Eq];
#pragma unroll
  for (int e = 0; e < Eq; e++) acc[e] = 0.f;

#pragma unroll
  for (int it = 0; it < Dq / 256; it++) {
    int d4 = it * 64 + lane;                 // float4 index within row
    float4 xv = xrow[d4];
    ushort4 o;
    o.x = f2bf(xv.x); o.y = f2bf(xv.y); o.z = f2bf(xv.z); o.w = f2bf(xv.w);
    orow[d4] = o;
    int d = d4 * 4;
#pragma unroll
    for (int e = 0; e < Eq; e++) {
      float4 wv = *(const float4*)&rwT[e * Dq + d];
      acc[e] += xv.x * wv.x + xv.y * wv.y + xv.z * wv.z + xv.w * wv.w;
    }
  }
#pragma unroll
  for (int e = 0; e < Eq; e++) {
    float v = acc[e];
#pragma unroll
    for (int off = 32; off; off >>= 1) v += __shfl_xor(v, off);
    acc[e] = v;
  }
  if (lane == 0) {
    float v1 = -1e30f, v2 = -1e30f; int i1 = 0, i2 = 0;
#pragma unroll
    for (int e = 0; e < Eq; e++) {
      float v = acc[e] + rb[e];
      if (v > v1)      { v2 = v1; i2 = i1; v1 = v; i1 = e; }
      else if (v > v2) { v2 = v;  i2 = e; }
    }
    float ex = expf(v2 - v1);
    float wa = 1.f / (1.f + ex);
    float wb = ex / (1.f + ex);
    tok_seg[token] = i1 | ((8 + i2) << 8);   // rank0 seg, rank1 seg
    tok_w[token] = make_float2(wa, wb);
  }
}

// ---------------- segment-list build, block-aggregated atomics.
__global__ __launch_bounds__(256) void scatter_build(
    const int* __restrict__ tok_seg, const float2* __restrict__ tok_w,
    int* __restrict__ cnt, int* __restrict__ seg_tok, float* __restrict__ seg_wgt)
{
  __shared__ int histA[16], histB[16], base[16];
  int t = threadIdx.x;
  if (t < 16) { histA[t] = 0; histB[t] = 0; }
  __syncthreads();
  int token = blockIdx.x * 256 + t;
  int sp = tok_seg[token];
  float2 wv = tok_w[token];
  int s0 = sp & 0xff, s1 = sp >> 8;
  atomicAdd(&histA[s0], 1);
  atomicAdd(&histA[s1], 1);
  __syncthreads();
  if (t < 16) base[t] = atomicAdd(&cnt[t], histA[t]);
  __syncthreads();
  int p0 = base[s0] + atomicAdd(&histB[s0], 1);
  seg_tok[(size_t)s0 * Mq + p0] = token;
  seg_wgt[(size_t)s0 * Mq + p0] = wv.x;
  int p1 = base[s1] + atomicAdd(&histB[s1], 1);
  seg_tok[(size_t)s1 * Mq + p1] = token;
  seg_wgt[(size_t)s1 * Mq + p1] = wv.y;
}

// ---------------- tile prefix over 16 segments (1 thread)
__global__ void prefix_kernel(const int* __restrict__ cnt, int* __restrict__ prefix)
{
  if (threadIdx.x == 0 && blockIdx.x == 0) {
    int t = 0;
#pragma unroll
    for (int s = 0; s < 16; s++) { prefix[s] = t; t += (cnt[s] + 127) >> 7; }
    prefix[16] = t;
  }
}

// ---------------- transpose+convert: in[R][C] f32 -> out[C][R] bf16, per expert z
__global__ __launch_bounds__(256) void transpose_cvt(
    const float* __restrict__ in, u16* __restrict__ out, int R, int C)
{
  __shared__ float tile[32][33];
  int e = blockIdx.z;
  in  += (size_t)e * R * C;
  out += (size_t)e * R * C;
  int c0 = blockIdx.x * 32, r0 = blockIdx.y * 32;
  int tx = threadIdx.x & 31, ty = threadIdx.x >> 5;   // ty 0..7
#pragma unroll
  for (int rr = 0; rr < 32; rr += 8)
    tile[rr + ty][tx] = in[(size_t)(r0 + rr + ty) * C + c0 + tx];
  __syncthreads();
#pragma unroll
  for (int rr = 0; rr < 32; rr += 8)
    out[(size_t)(c0 + rr + ty) * R + r0 + tx] = f2bf(tile[tx][rr + ty]);
}

// ---------------- grouped bf16 GEMM, 128x256 tile, 8 waves (2Mx4N).
// Phase-pipelined K-loop (T3/T4/T5, m201 discipline): 4-deep half-tile LDS
// ring (BK=32 units, 96 KB), loads prefetched 3 half-tiles ahead, steady-state
// s_waitcnt vmcnt(6) (never 0 mid-loop), ONE barrier per phase (reuse
// distance 4 makes write-after-read safe), setprio(1) around the MFMA cluster.
// XCD co-location: bijective lid->(tile,panel), panel-blocks of a tile share
// an XCD (lid&7) -> A-tile L2-resident. LDS swizzled both-sides (rule 21).
// EPI 0 (GEMM1): Hout[lt][c] = bf16(gelu(acc + b1))
// EPI 1 (GEMM2): out[token][c] += (acc + b2[c]) * w   (HW f32 atomic onto
//                pre-zeroed out; commutative adds -> deterministic)
template<int EPI>
__global__ __launch_bounds__(512) void moe_gemm(
    const u16* __restrict__ A, const u16* __restrict__ W,
    const float* __restrict__ bias,
    u16* __restrict__ Hout, float* __restrict__ out,
    const int* __restrict__ cnt, const int* __restrict__ prefix,
    const int* __restrict__ seg_tok, const float* __restrict__ seg_wgt,
    int K, int N, int tile_lo)
{
  const int NP = N / 256;               // panels: 12 (GEMM1) or 3 (GEMM2)
  const int lid = (int)blockIdx.x + NP * (int)blockIdx.y;
  const int xcd = lid & 7, slot = lid >> 3;
  const int t_loc = xcd + 8 * (slot / NP);   // chunk-local tile (gridDim.y%8==0)
  const int panel = slot % NP;

  const int t = tile_lo + t_loc;
  const int total = prefix[16];
  if (t >= total) return;
  int seg = 0;
#pragma unroll
  for (int s = 1; s < 16; s++) if (prefix[s] <= t) seg = s;
  const int e = seg & 7;
  const int segcnt = cnt[seg];
  const int ti = t - prefix[seg];       // tile within segment
  const int lt = t_loc;                 // local tile (Hbuf)

  __shared__ u16 As[4][128 * 32];       // 4 x 8 KB half-tile ring
  __shared__ u16 Bs[4][256 * 32];       // 4 x 16 KB half-tile ring
  const int tid  = threadIdx.x;
  const int lane = tid & 63;
  const int wid  = tid >> 6;            // 0..7
  const int wr   = wid >> 2, wc = wid & 3;   // 2 x 4 waves
  const int lrow = lane & 15, kgrp = lane >> 4;
  const int kx   = kgrp ^ ((lrow >> 1) & 3);   // swizzled read chunk
  const int n0 = panel * 256;

  f32x4 acc[4][4];
#pragma unroll
  for (int m = 0; m < 4; m++)
#pragma unroll
    for (int n = 0; n < 4; n++) acc[m][n] = (f32x4){0.f, 0.f, 0.f, 0.f};

  // staging: A row = tid>>2 (1 gload), B rows tid>>2 and +128 (2 gloads);
  // source k-chunk swizzled by row ((tid>>3)&3 == (row>>1)&3 for all three).
  const int r0 = tid >> 2;
  const int kc = (((tid & 3) ^ ((tid >> 3) & 3)) * 8);
  const u16 *gA0;
  if (EPI == 0) {
    int i0 = ti * 128 + r0;
    int tok0 = (i0 < segcnt) ? seg_tok[(size_t)seg * Mq + i0] : 0;
    gA0 = A + (size_t)tok0 * K + kc;
  } else {
    gA0 = A + (size_t)(lt * 128 + r0) * K + kc;
  }
  const u16* gB = W + (size_t)e * K * N + (size_t)(n0 + r0) * K + kc;
  const size_t rowskipB = (size_t)128 * K;
  const int lofs = tid * 8;

  auto stage = [&](int b) {
    gload16(gA0, &As[b][lofs]);
    gload16(gB,            &Bs[b][lofs]);
    gload16(gB + rowskipB, &Bs[b][lofs + 4096]);
    gA0 += 32; gB += 32;
  };

  // one phase: ds_read Hp; optional stage(H[p+3]); counted vmcnt; MFMA; barrier
  auto phase = [&](int p, int vm) {
    const int buf = p & 3;
    bf16x8 a[4], b[4];
#pragma unroll
    for (int m = 0; m < 4; m++)
      a[m] = *(const bf16x8*)&As[buf][(wr * 64 + m * 16 + lrow) * 32 + kx * 8];
#pragma unroll
    for (int n = 0; n < 4; n++)
      b[n] = *(const bf16x8*)&Bs[buf][(wc * 64 + n * 16 + lrow) * 32 + kx * 8];
    if (vm == 6) {
      stage((p + 3) & 3);
      asm volatile("s_waitcnt vmcnt(6)" ::: "memory");   // H[p+1] landed
    } else if (vm == 3) {
      asm volatile("s_waitcnt vmcnt(3)" ::: "memory");
    } else if (vm == 0) {
      asm volatile("s_waitcnt vmcnt(0)" ::: "memory");
    }
    __builtin_amdgcn_sched_barrier(0);
    __builtin_amdgcn_s_setprio(1);
#pragma unroll
    for (int m = 0; m < 4; m++)
#pragma unroll
      for (int n = 0; n < 4; n++)
        acc[m][n] = __builtin_amdgcn_mfma_f32_16x16x32_bf16(a[m], b[n], acc[m][n], 0, 0, 0);
    __builtin_amdgcn_s_setprio(0);
    __builtin_amdgcn_sched_barrier(0);
    __builtin_amdgcn_s_barrier();       // phase end
  };

  const int NPH = K / 32;
  stage(0); stage(1); stage(2);         // prefetch 3 half-tiles (9 loads)
  asm volatile("s_waitcnt vmcnt(6)" ::: "memory");   // H0 landed
  __builtin_amdgcn_s_barrier();
  int p = 0;
  for (; p < NPH - 3; ++p) phase(p, 6);
  phase(p, 3); ++p;
  phase(p, 0); ++p;
  phase(p, -1);

  const int rbase = wr * 64;
  const int cbase = n0 + wc * 64;
  if (EPI == 0) {
#pragma unroll
    for (int n = 0; n < 4; n++) {
      int c = cbase + n * 16 + lrow;
      float bv = bias[(size_t)e * N + c];
#pragma unroll
      for (int m = 0; m < 4; m++)
#pragma unroll
        for (int j = 0; j < 4; j++) {
          int r = rbase + m * 16 + kgrp * 4 + j;
          float v = acc[m][n][j] + bv;
          Hout[(size_t)(lt * 128 + r) * N + c] = f2bf(gelu_f(v));
        }
    }
  } else {
#pragma unroll
    for (int m = 0; m < 4; m++)
#pragma unroll
      for (int j = 0; j < 4; j++) {
        int r = rbase + m * 16 + kgrp * 4 + j;
        int i = ti * 128 + r;
        if (i < segcnt) {
          int token = seg_tok[(size_t)seg * Mq + i];
          float w = seg_wgt[(size_t)seg * Mq + i];
          float* orow = out + (size_t)token * Oq;
#pragma unroll
          for (int n = 0; n < 4; n++) {
            int c = cbase + n * 16 + lrow;
            float v = (acc[m][n][j] + bias[(size_t)e * N + c]) * w;
            unsafeAtomicAdd(&orow[c], v);
          }
        }
      }
  }
}

// ---------------- in-place LayerNorm, one wave per row
__global__ __launch_bounds__(256) void ln_kernel(
    float* __restrict__ io, const float* __restrict__ g, const float* __restrict__ b)
{
  int wid = threadIdx.x >> 6, lane = threadIdx.x & 63;
  int row = blockIdx.x * 4 + wid;
  float* p = io + (size_t)row * Oq;
  float v[Oq / 64];
  float s = 0.f;
#pragma unroll
  for (int i = 0; i < Oq / 64; i++) { v[i] = p[lane + i * 64]; s += v[i]; }
#pragma unroll
  for (int off = 32; off; off >>= 1) s += __shfl_xor(s, off);
  float mu = s * (1.0f / Oq);
  float q = 0.f;
#pragma unroll
  for (int i = 0; i < Oq / 64; i++) { float d = v[i] - mu; q += d * d; }
#pragma unroll
  for (int off = 32; off; off >>= 1) q += __shfl_xor(q, off);
  float inv = rsqrtf(q * (1.0f / Oq) + LN_EPS);
#pragma unroll
  for (int i = 0; i < Oq / 64; i++) {
    int c = lane + i * 64;
    p[c] = (v[i] - mu) * inv * g[c] + b[c];
  }
}

extern "C" void kernel_launch(void* const* d_in, const int* in_sizes, int n_in,
                              void* d_out, int out_size, void* d_ws, size_t ws_size,
                              hipStream_t stream)
{
  const float* x    = (const float*)d_in[0];
  const float* rw   = (const float*)d_in[1];
  const float* rb   = (const float*)d_in[2];
  const float* w1   = (const float*)d_in[3];
  const float* b1   = (const float*)d_in[4];
  const float* w2   = (const float*)d_in[5];
  const float* b2   = (const float*)d_in[6];
  const float* ln_g = (const float*)d_in[7];
  const float* ln_b = (const float*)d_in[8];
  float* out = (float*)d_out;

  char* ws = (char*)d_ws;
  size_t off = 0;
  auto alloc = [&](size_t bytes) {
    void* p = ws + off;
    off += (bytes + 255) & ~(size_t)255;
    return p;
  };
  int*    cnt     = (int*)alloc(16 * 4);
  int*    prefix  = (int*)alloc(17 * 4);
  int*    tok_seg = (int*)alloc((size_t)Mq * 4);
  float2* tok_w   = (float2*)alloc((size_t)Mq * 8);
  int*    seg_tok = (int*)alloc((size_t)16 * Mq * 4);
  float*  seg_wgt = (float*)alloc((size_t)16 * Mq * 4);
  u16* Xbf = (u16*)alloc((size_t)Mq * Dq * 2);
  u16* W1T = (u16*)alloc((size_t)Eq * Dq * Hq * 2);
  u16* W2T = (u16*)alloc((size_t)Eq * Hq * Oq * 2);

  size_t remain = (ws_size > off) ? ws_size - off : 0;
  size_t tile_bytes = (size_t)128 * Hq * 2;   // 768 KB per slot-tile
  long long wt = (long long)(remain / tile_bytes);
  if (wt > MAX_TILES) wt = MAX_TILES;
  wt &= ~7LL;                 // multiple of 8 for the XCD remap bijection
  if (wt < 8) wt = 8;
  int WT = (int)wt;
  u16* Hbuf = (u16*)alloc((size_t)WT * tile_bytes);

  hipMemsetAsync(out, 0, (size_t)Mq * Oq * 4, stream);
  hipMemsetAsync(cnt, 0, 16 * 4, stream);
  router_cvt_kernel<<<Mq / 4, 256, 0, stream>>>(x, rw, rb, Xbf, tok_seg, tok_w);
  scatter_build<<<Mq / 256, 256, 0, stream>>>(tok_seg, tok_w, cnt, seg_tok, seg_wgt);
  prefix_kernel<<<1, 64, 0, stream>>>(cnt, prefix);
  transpose_cvt<<<dim3(Hq / 32, Dq / 32, Eq), 256, 0, stream>>>(w1, W1T, Dq, Hq);
  transpose_cvt<<<dim3(Oq / 32, Hq / 32, Eq), 256, 0, stream>>>(w2, W2T, Hq, Oq);

  for (int tl = 0; tl < MAX_TILES; tl += WT) {
    int gx = MAX_TILES - tl; if (gx > WT) gx = WT;   // stays multiple of 8
    moe_gemm<0><<<dim3(Hq / 256, gx), 512, 0, stream>>>(
        Xbf, W1T, b1, Hbuf, nullptr, cnt, prefix, seg_tok, seg_wgt,
        Dq, Hq, tl);
    moe_gemm<1><<<dim3(Oq / 256, gx), 512, 0, stream>>>(
        Hbuf, W2T, b2, nullptr, out, cnt, prefix, seg_tok, seg_wgt,
        Hq, Oq, tl);
  }
  ln_kernel<<<Mq / 4, 256, 0, stream>>>(out, ln_g, ln_b);
}

// Round 14
// 755.088 us; speedup vs baseline: 1.0398x; 1.0398x over previous
//
#include <hip/hip_runtime.h>
#include <hip/hip_bf16.h>
#include <stdint.h>

#define Bq  8
#define Sq  2048
#define Dq  768
#define Hq  3072
#define Oq  768
#define Eq  8
#define Mq  (Bq*Sq)            // 16384 tokens
#define LN_EPS 1e-5f
#define MAX_T256 (Mq/128 + 16)      // 144 worst-case padded 256-row tiles

typedef unsigned short u16;
typedef __attribute__((ext_vector_type(4))) float f32x4;
typedef __attribute__((ext_vector_type(8))) __bf16 bf16x8;

static __device__ __forceinline__ u16 f2bf(float f) {
  __hip_bfloat16 h = __float2bfloat16(f);
  return __builtin_bit_cast(u16, h);
}

static __device__ __forceinline__ float gelu_f(float x) {
  float u = 0.7978845608028654f * x * (1.0f + 0.044715f * x * x);
  float e = __expf(2.0f * u);
  float t = 1.0f - 2.0f / (e + 1.0f);   // tanh(u), NaN-free
  return 0.5f * x * (1.0f + t);
}

typedef const __attribute__((address_space(1))) void* gas_t;
typedef __attribute__((address_space(3))) void* las_t;
static __device__ __forceinline__ void gload16(const void* g, void* l) {
  __builtin_amdgcn_global_load_lds((gas_t)g, (las_t)l, 16, 0, 0);
}

// ---------------- fused router + fp32->bf16 convert. NO atomics.
__global__ __launch_bounds__(256) void router_cvt_kernel(
    const float* __restrict__ x, const float* __restrict__ rw,
    const float* __restrict__ rb, u16* __restrict__ Xbf,
    int* __restrict__ tok_seg, float2* __restrict__ tok_w)
{
  __shared__ float rwT[Eq * Dq];
  for (int i = threadIdx.x; i < Eq * Dq; i += 256)
    rwT[(i & 7) * Dq + (i >> 3)] = rw[i];
  __syncthreads();

  int wid = threadIdx.x >> 6;
  int lane = threadIdx.x & 63;
  int token = blockIdx.x * 4 + wid;
  const float4* xrow = (const float4*)(x + (size_t)token * Dq);
  ushort4* orow = (ushort4*)(Xbf + (size_t)token * Dq);

  float acc[Eq];
#pragma unroll
  for (int e = 0; e < Eq; e++) acc[e] = 0.f;

#pragma unroll
  for (int it = 0; it < Dq / 256; it++) {
    int d4 = it * 64 + lane;
    float4 xv = xrow[d4];
    ushort4 o;
    o.x = f2bf(xv.x); o.y = f2bf(xv.y); o.z = f2bf(xv.z); o.w = f2bf(xv.w);
    orow[d4] = o;
    int d = d4 * 4;
#pragma unroll
    for (int e = 0; e < Eq; e++) {
      float4 wv = *(const float4*)&rwT[e * Dq + d];
      acc[e] += xv.x * wv.x + xv.y * wv.y + xv.z * wv.z + xv.w * wv.w;
    }
  }
#pragma unroll
  for (int e = 0; e < Eq; e++) {
    float v = acc[e];
#pragma unroll
    for (int off = 32; off; off >>= 1) v += __shfl_xor(v, off);
    acc[e] = v;
  }
  if (lane == 0) {
    float v1 = -1e30f, v2 = -1e30f; int i1 = 0, i2 = 0;
#pragma unroll
    for (int e = 0; e < Eq; e++) {
      float v = acc[e] + rb[e];
      if (v > v1)      { v2 = v1; i2 = i1; v1 = v; i1 = e; }
      else if (v > v2) { v2 = v;  i2 = e; }
    }
    float ex = expf(v2 - v1);
    float wa = 1.f / (1.f + ex);
    float wb = ex / (1.f + ex);
    tok_seg[token] = i1 | ((8 + i2) << 8);
    tok_w[token] = make_float2(wa, wb);
  }
}

// ---------------- segment-list build, block-aggregated atomics.
__global__ __launch_bounds__(256) void scatter_build(
    const int* __restrict__ tok_seg, const float2* __restrict__ tok_w,
    int* __restrict__ cnt, int* __restrict__ seg_tok, float* __restrict__ seg_wgt)
{
  __shared__ int histA[16], histB[16], base[16];
  int t = threadIdx.x;
  if (t < 16) { histA[t] = 0; histB[t] = 0; }
  __syncthreads();
  int token = blockIdx.x * 256 + t;
  int sp = tok_seg[token];
  float2 wv = tok_w[token];
  int s0 = sp & 0xff, s1 = sp >> 8;
  atomicAdd(&histA[s0], 1);
  atomicAdd(&histA[s1], 1);
  __syncthreads();
  if (t < 16) base[t] = atomicAdd(&cnt[t], histA[t]);
  __syncthreads();
  int p0 = base[s0] + atomicAdd(&histB[s0], 1);
  seg_tok[(size_t)s0 * Mq + p0] = token;
  seg_wgt[(size_t)s0 * Mq + p0] = wv.x;
  int p1 = base[s1] + atomicAdd(&histB[s1], 1);
  seg_tok[(size_t)s1 * Mq + p1] = token;
  seg_wgt[(size_t)s1 * Mq + p1] = wv.y;
}

// ---------------- tile prefix over 16 segments, 256-row padding
__global__ void prefix_kernel(const int* __restrict__ cnt, int* __restrict__ prefix)
{
  if (threadIdx.x == 0 && blockIdx.x == 0) {
    int t = 0;
#pragma unroll
    for (int s = 0; s < 16; s++) { prefix[s] = t; t += (cnt[s] + 255) >> 8; }
    prefix[16] = t;
  }
}

// ---------------- transpose+convert: in[R][C] f32 -> out[C][R] bf16, per expert z
__global__ __launch_bounds__(256) void transpose_cvt(
    const float* __restrict__ in, u16* __restrict__ out, int R, int C)
{
  __shared__ float tile[32][33];
  int e = blockIdx.z;
  in  += (size_t)e * R * C;
  out += (size_t)e * R * C;
  int c0 = blockIdx.x * 32, r0 = blockIdx.y * 32;
  int tx = threadIdx.x & 31, ty = threadIdx.x >> 5;
#pragma unroll
  for (int rr = 0; rr < 32; rr += 8)
    tile[rr + ty][tx] = in[(size_t)(r0 + rr + ty) * C + c0 + tx];
  __syncthreads();
#pragma unroll
  for (int rr = 0; rr < 32; rr += 8)
    out[(size_t)(c0 + rr + ty) * R + r0 + tx] = f2bf(tile[tx][rr + ty]);
}

// ---------------- GEMM1: 256x256 tile, 8 waves (2Mx4N), BK=64, m201-style
// 8-phase schedule. LDS 128KB: 2-slot dbuf, each slot A[256][64]+B[256][64].
// Per iter (one K-tile): 4 phases x {ds_read a-frags; stage one half-tile of
// next K-tile (2 gloads); 16 MFMA with setprio; barrier}. vmcnt(2) ONCE per
// K-tile at phase 0, placed BEFORE that tile's first ds_read. ds_read->MFMA
// waits left to the compiler (no manual lgkmcnt).
// XCD co-location: panel-blocks of one tile share an XCD.
// LDS swizzle both-sides: global k-chunk XOR (row&7); read XOR identical.
__global__ __launch_bounds__(512, 2) void moe_gemm1(
    const u16* __restrict__ A, const u16* __restrict__ W,
    const float* __restrict__ bias, u16* __restrict__ Hout,
    const int* __restrict__ cnt, const int* __restrict__ prefix,
    const int* __restrict__ seg_tok, int K, int N, int tile_lo)
{
  const int NP = N / 256;               // 12 panels
  const int lid = (int)blockIdx.x + NP * (int)blockIdx.y;
  const int xcd = lid & 7, slot = lid >> 3;
  const int t_loc = xcd + 8 * (slot / NP);   // gridDim.y multiple of 8
  const int panel = slot % NP;

  const int t = tile_lo + t_loc;
  if (t >= prefix[16]) return;
  int seg = 0;
#pragma unroll
  for (int s = 1; s < 16; s++) if (prefix[s] <= t) seg = s;
  const int e = seg & 7;
  const int segcnt = cnt[seg];
  const int ti = t - prefix[seg];
  const int lt = t_loc;

  __shared__ u16 As[2][16384];          // [2][256 rows][8 granules][8]
  __shared__ u16 Bs[2][16384];
  const int tid  = threadIdx.x;
  const int lane = tid & 63;
  const int wid  = tid >> 6;
  const int wr   = wid >> 2, wc = wid & 3;    // 2M x 4N waves
  const int lrow = lane & 15, kgrp = lane >> 4;
  const int gcx0 = ((kgrp)     ^ (lrow & 7)) * 8;   // kk=0 chunk (elems)
  const int gcx1 = ((4 + kgrp) ^ (lrow & 7)) * 8;   // kk=1

  f32x4 acc[8][4];
#pragma unroll
  for (int m = 0; m < 8; m++)
#pragma unroll
    for (int n = 0; n < 4; n++) acc[m][n] = (f32x4){0.f, 0.f, 0.f, 0.f};

  // staging: 8 threads/row (chunk = tid&7), 64 rows per gload call.
  const int srow = tid >> 3;
  const int swz  = ((tid & 7) ^ (srow & 7)) * 8;
  // A source rows (token gather), 4 (half,call) pairs
  const u16 *pA00, *pA01, *pA10, *pA11, *pB00, *pB01, *pB10, *pB11;
  {
    int sr;
    sr = ti * 256 +   0 +  0 + srow;
    pA00 = A + (size_t)((sr < segcnt) ? seg_tok[(size_t)seg * Mq + sr] : 0) * K + swz;
    sr = ti * 256 +   0 + 64 + srow;
    pA01 = A + (size_t)((sr < segcnt) ? seg_tok[(size_t)seg * Mq + sr] : 0) * K + swz;
    sr = ti * 256 + 128 +  0 + srow;
    pA10 = A + (size_t)((sr < segcnt) ? seg_tok[(size_t)seg * Mq + sr] : 0) * K + swz;
    sr = ti * 256 + 128 + 64 + srow;
    pA11 = A + (size_t)((sr < segcnt) ? seg_tok[(size_t)seg * Mq + sr] : 0) * K + swz;
    const u16* Wb = W + (size_t)e * K * N;
    pB00 = Wb + (size_t)(panel * 256 +   0 +  0 + srow) * K + swz;
    pB01 = Wb + (size_t)(panel * 256 +   0 + 64 + srow) * K + swz;
    pB10 = Wb + (size_t)(panel * 256 + 128 +  0 + srow) * K + swz;
    pB11 = Wb + (size_t)(panel * 256 + 128 + 64 + srow) * K + swz;
  }

#define STG(buf, h, P0, P1)                                \
  do {                                                     \
    gload16(P0, &(buf)[(h) * 8192 + tid * 8]);             \
    gload16(P1, &(buf)[(h) * 8192 + 4096 + tid * 8]);      \
    P0 += 64; P1 += 64;                                    \
  } while (0)

  const int NKT = K / 64;               // 12 K-tiles
  // prologue: stage tile 0 into slot 0 (8 loads/thread)
  STG(As[0], 0, pA00, pA01); STG(As[0], 1, pA10, pA11);
  STG(Bs[0], 0, pB00, pB01); STG(Bs[0], 1, pB10, pB11);

  bf16x8 bfr[4][2];
  for (int kt = 0; kt < NKT; ++kt) {
    const int s = kt & 1, d = s ^ 1;
    const bool more = (kt + 1 < NKT);
    const int abase = wr * 128 + lrow;
    const int bbase = wc * 64 + lrow;

    // ---- phase 0: ensure tile kt landed; read all b-frags + a(m=0,1)
    if (more) {
      STG(As[d], 0, pA00, pA01);
      asm volatile("s_waitcnt vmcnt(2)" ::: "memory");
    } else {
      asm volatile("s_waitcnt vmcnt(0)" ::: "memory");
    }
    __builtin_amdgcn_s_barrier();
    __builtin_amdgcn_sched_barrier(0);
#pragma unroll
    for (int n = 0; n < 4; n++) {
      bfr[n][0] = *(const bf16x8*)&Bs[s][(bbase + n * 16) * 64 + gcx0];
      bfr[n][1] = *(const bf16x8*)&Bs[s][(bbase + n * 16) * 64 + gcx1];
    }
    {
      bf16x8 a00 = *(const bf16x8*)&As[s][(abase +  0) * 64 + gcx0];
      bf16x8 a01 = *(const bf16x8*)&As[s][(abase +  0) * 64 + gcx1];
      bf16x8 a10 = *(const bf16x8*)&As[s][(abase + 16) * 64 + gcx0];
      bf16x8 a11 = *(const bf16x8*)&As[s][(abase + 16) * 64 + gcx1];
      __builtin_amdgcn_s_setprio(1);
#pragma unroll
      for (int n = 0; n < 4; n++) {
        acc[0][n] = __builtin_amdgcn_mfma_f32_16x16x32_bf16(a00, bfr[n][0], acc[0][n], 0, 0, 0);
        acc[0][n] = __builtin_amdgcn_mfma_f32_16x16x32_bf16(a01, bfr[n][1], acc[0][n], 0, 0, 0);
        acc[1][n] = __builtin_amdgcn_mfma_f32_16x16x32_bf16(a10, bfr[n][0], acc[1][n], 0, 0, 0);
        acc[1][n] = __builtin_amdgcn_mfma_f32_16x16x32_bf16(a11, bfr[n][1], acc[1][n], 0, 0, 0);
      }
      __builtin_amdgcn_s_setprio(0);
    }
    __builtin_amdgcn_sched_barrier(0);
    __builtin_amdgcn_s_barrier();

    // ---- phases 1..3: a(m=2q,2q+1); stage next half-tile; 16 MFMA
#define PHASE(q, STGSTMT)                                                     \
    do {                                                                      \
      bf16x8 a00 = *(const bf16x8*)&As[s][(abase + (2*(q))    * 16) * 64 + gcx0]; \
      bf16x8 a01 = *(const bf16x8*)&As[s][(abase + (2*(q))    * 16) * 64 + gcx1]; \
      bf16x8 a10 = *(const bf16x8*)&As[s][(abase + (2*(q)+1)  * 16) * 64 + gcx0]; \
      bf16x8 a11 = *(const bf16x8*)&As[s][(abase + (2*(q)+1)  * 16) * 64 + gcx1]; \
      if (more) { STGSTMT; }                                                  \
      __builtin_amdgcn_s_setprio(1);                                          \
      _Pragma("unroll")                                                       \
      for (int n = 0; n < 4; n++) {                                           \
        acc[2*(q)][n]   = __builtin_amdgcn_mfma_f32_16x16x32_bf16(a00, bfr[n][0], acc[2*(q)][n], 0, 0, 0);   \
        acc[2*(q)][n]   = __builtin_amdgcn_mfma_f32_16x16x32_bf16(a01, bfr[n][1], acc[2*(q)][n], 0, 0, 0);   \
        acc[2*(q)+1][n] = __builtin_amdgcn_mfma_f32_16x16x32_bf16(a10, bfr[n][0], acc[2*(q)+1][n], 0, 0, 0); \
        acc[2*(q)+1][n] = __builtin_amdgcn_mfma_f32_16x16x32_bf16(a11, bfr[n][1], acc[2*(q)+1][n], 0, 0, 0); \
      }                                                                       \
      __builtin_amdgcn_s_setprio(0);                                          \
      __builtin_amdgcn_sched_barrier(0);                                      \
      __builtin_amdgcn_s_barrier();                                           \
    } while (0)

    PHASE(1, STG(As[d], 1, pA10, pA11));
    PHASE(2, STG(Bs[d], 0, pB00, pB01));
    PHASE(3, STG(Bs[d], 1, pB10, pB11));
#undef PHASE
  }

  // epilogue: Hout[lt*256 + r][c] = bf16(gelu(acc + b1))
  const int rbase = wr * 128;
  const int cbase = panel * 256 + wc * 64;
#pragma unroll
  for (int n = 0; n < 4; n++) {
    int c = cbase + n * 16 + lrow;
    float bv = bias[(size_t)e * N + c];
#pragma unroll
    for (int m = 0; m < 8; m++)
#pragma unroll
      for (int j = 0; j < 4; j++) {
        int r = rbase + m * 16 + kgrp * 4 + j;
        float v = acc[m][n][j] + bv;
        Hout[(size_t)(lt * 256 + r) * N + c] = f2bf(gelu_f(v));
      }
  }
#undef STG
}

// ---------------- GEMM2: proven round-10 structure (128x128, 4 waves, 2-deep
// dbuf, vmcnt(4)), mapped onto 256-padded tiles as 128-sub-tiles.
__global__ __launch_bounds__(256) void moe_gemm2(
    const u16* __restrict__ A, const u16* __restrict__ W,
    const float* __restrict__ bias, float* __restrict__ out,
    const int* __restrict__ cnt, const int* __restrict__ prefix,
    const int* __restrict__ seg_tok, const float* __restrict__ seg_wgt,
    int K, int N, int tile_lo)
{
  const int NP = N / 128;               // 6 panels
  const int lid = (int)blockIdx.x + NP * (int)blockIdx.y;
  const int xcd = lid & 7, slot = lid >> 3;
  const int t2 = xcd + 8 * (slot / NP);      // 128-sub-tile, gridDim.y%8==0
  const int panel = slot % NP;

  const int t256 = tile_lo + (t2 >> 1);
  if (t256 >= prefix[16]) return;
  int seg = 0;
#pragma unroll
  for (int s = 1; s < 16; s++) if (prefix[s] <= t256) seg = s;
  const int e = seg & 7;
  const int segcnt = cnt[seg];
  const int ti = (t256 - prefix[seg]) * 2 + (t2 & 1);  // 128-tile in segment
  const int lt = t2;                                   // Hbuf 128-row index

  __shared__ u16 As[2][128 * 32];
  __shared__ u16 Bs[2][128 * 32];
  const int tid  = threadIdx.x;
  const int lane = tid & 63;
  const int wid  = tid >> 6;
  const int wr   = wid >> 1, wc = wid & 1;
  const int lrow = lane & 15, kgrp = lane >> 4;
  const int kx   = kgrp ^ ((lrow >> 1) & 3);
  const int n0 = panel * 128;

  f32x4 acc[4][4];
#pragma unroll
  for (int m = 0; m < 4; m++)
#pragma unroll
    for (int n = 0; n < 4; n++) acc[m][n] = (f32x4){0.f, 0.f, 0.f, 0.f};

  const int r0 = tid >> 2;
  const int kc = (((tid & 3) ^ ((tid >> 3) & 3)) * 8);
  const u16* gA0 = A + (size_t)(lt * 128 + r0) * K + kc;
  const u16* gA1 = gA0 + (size_t)64 * K;
  const u16* gB = W + (size_t)e * K * N + (size_t)(n0 + r0) * K + kc;
  const size_t rowskipB = (size_t)64 * K;
  const int lofs = tid * 8;

  auto stage = [&](int b) {
    gload16(gA0, &As[b][lofs]);
    gload16(gA1, &As[b][lofs + 2048]);
    gload16(gB,            &Bs[b][lofs]);
    gload16(gB + rowskipB, &Bs[b][lofs + 2048]);
    gA0 += 32; gA1 += 32; gB += 32;
  };

  const int NIT = K / 32;
  stage(0);
  for (int it = 0; it < NIT; ++it) {
    const int cur = it & 1;
    if (it + 1 < NIT) {
      stage(cur ^ 1);
      asm volatile("s_waitcnt vmcnt(4)" ::: "memory");
    } else {
      asm volatile("s_waitcnt vmcnt(0)" ::: "memory");
    }
    __builtin_amdgcn_s_barrier();
    __builtin_amdgcn_sched_barrier(0);
    bf16x8 a[4], b[4];
#pragma unroll
    for (int m = 0; m < 4; m++)
      a[m] = *(const bf16x8*)&As[cur][(wr * 64 + m * 16 + lrow) * 32 + kx * 8];
#pragma unroll
    for (int n = 0; n < 4; n++)
      b[n] = *(const bf16x8*)&Bs[cur][(wc * 64 + n * 16 + lrow) * 32 + kx * 8];
#pragma unroll
    for (int m = 0; m < 4; m++)
#pragma unroll
      for (int n = 0; n < 4; n++)
        acc[m][n] = __builtin_amdgcn_mfma_f32_16x16x32_bf16(a[m], b[n], acc[m][n], 0, 0, 0);
    __builtin_amdgcn_sched_barrier(0);
    __builtin_amdgcn_s_barrier();
  }

  const int rbase = wr * 64;
  const int cbase = n0 + wc * 64;
#pragma unroll
  for (int m = 0; m < 4; m++)
#pragma unroll
    for (int j = 0; j < 4; j++) {
      int r = rbase + m * 16 + kgrp * 4 + j;
      int i = ti * 128 + r;
      if (i < segcnt) {
        int token = seg_tok[(size_t)seg * Mq + i];
        float w = seg_wgt[(size_t)seg * Mq + i];
        float* orow = out + (size_t)token * Oq;
#pragma unroll
        for (int n = 0; n < 4; n++) {
          int c = cbase + n * 16 + lrow;
          float v = (acc[m][n][j] + bias[(size_t)e * N + c]) * w;
          unsafeAtomicAdd(&orow[c], v);
        }
      }
    }
}

// ---------------- in-place LayerNorm, one wave per row
__global__ __launch_bounds__(256) void ln_kernel(
    float* __restrict__ io, const float* __restrict__ g, const float* __restrict__ b)
{
  int wid = threadIdx.x >> 6, lane = threadIdx.x & 63;
  int row = blockIdx.x * 4 + wid;
  float* p = io + (size_t)row * Oq;
  float v[Oq / 64];
  float s = 0.f;
#pragma unroll
  for (int i = 0; i < Oq / 64; i++) { v[i] = p[lane + i * 64]; s += v[i]; }
#pragma unroll
  for (int off = 32; off; off >>= 1) s += __shfl_xor(s, off);
  float mu = s * (1.0f / Oq);
  float q = 0.f;
#pragma unroll
  for (int i = 0; i < Oq / 64; i++) { float d = v[i] - mu; q += d * d; }
#pragma unroll
  for (int off = 32; off; off >>= 1) q += __shfl_xor(q, off);
  float inv = rsqrtf(q * (1.0f / Oq) + LN_EPS);
#pragma unroll
  for (int i = 0; i < Oq / 64; i++) {
    int c = lane + i * 64;
    p[c] = (v[i] - mu) * inv * g[c] + b[c];
  }
}

extern "C" void kernel_launch(void* const* d_in, const int* in_sizes, int n_in,
                              void* d_out, int out_size, void* d_ws, size_t ws_size,
                              hipStream_t stream)
{
  const float* x    = (const float*)d_in[0];
  const float* rw   = (const float*)d_in[1];
  const float* rb   = (const float*)d_in[2];
  const float* w1   = (const float*)d_in[3];
  const float* b1   = (const float*)d_in[4];
  const float* w2   = (const float*)d_in[5];
  const float* b2   = (const float*)d_in[6];
  const float* ln_g = (const float*)d_in[7];
  const float* ln_b = (const float*)d_in[8];
  float* out = (float*)d_out;

  char* ws = (char*)d_ws;
  size_t off = 0;
  auto alloc = [&](size_t bytes) {
    void* p = ws + off;
    off += (bytes + 255) & ~(size_t)255;
    return p;
  };
  int*    cnt     = (int*)alloc(16 * 4);
  int*    prefix  = (int*)alloc(17 * 4);
  int*    tok_seg = (int*)alloc((size_t)Mq * 4);
  float2* tok_w   = (float2*)alloc((size_t)Mq * 8);
  int*    seg_tok = (int*)alloc((size_t)16 * Mq * 4);
  float*  seg_wgt = (float*)alloc((size_t)16 * Mq * 4);
  u16* Xbf = (u16*)alloc((size_t)Mq * Dq * 2);
  u16* W1T = (u16*)alloc((size_t)Eq * Dq * Hq * 2);
  u16* W2T = (u16*)alloc((size_t)Eq * Hq * Oq * 2);

  size_t remain = (ws_size > off) ? ws_size - off : 0;
  size_t tile_bytes = (size_t)256 * Hq * 2;   // 1.5 MB per 256-row tile
  long long wt = (long long)(remain / tile_bytes);
  if (wt > MAX_T256) wt = MAX_T256;
  wt &= ~7LL;                 // multiple of 8 for the XCD remap bijection
  if (wt < 8) wt = 8;
  int WT = (int)wt;
  u16* Hbuf = (u16*)alloc((size_t)WT * tile_bytes);

  hipMemsetAsync(out, 0, (size_t)Mq * Oq * 4, stream);
  hipMemsetAsync(cnt, 0, 16 * 4, stream);
  router_cvt_kernel<<<Mq / 4, 256, 0, stream>>>(x, rw, rb, Xbf, tok_seg, tok_w);
  scatter_build<<<Mq / 256, 256, 0, stream>>>(tok_seg, tok_w, cnt, seg_tok, seg_wgt);
  prefix_kernel<<<1, 64, 0, stream>>>(cnt, prefix);
  transpose_cvt<<<dim3(Hq / 32, Dq / 32, Eq), 256, 0, stream>>>(w1, W1T, Dq, Hq);
  transpose_cvt<<<dim3(Oq / 32, Hq / 32, Eq), 256, 0, stream>>>(w2, W2T, Hq, Oq);

  for (int tl = 0; tl < MAX_T256; tl += WT) {
    int gx = MAX_T256 - tl; if (gx > WT) gx = WT;   // stays multiple of 8
    moe_gemm1<<<dim3(Hq / 256, gx), 512, 0, stream>>>(
        Xbf, W1T, b1, Hbuf, cnt, prefix, seg_tok, Dq, Hq, tl);
    moe_gemm2<<<dim3(Oq / 128, 2 * gx), 256, 0, stream>>>(
        Hbuf, W2T, b2, out, cnt, prefix, seg_tok, seg_wgt, Hq, Oq, tl);
  }
  ln_kernel<<<Mq / 4, 256, 0, stream>>>(out, ln_g, ln_b);
}

// Round 15
// 735.544 us; speedup vs baseline: 1.0675x; 1.0266x over previous
//
#include <hip/hip_runtime.h>
#include <hip/hip_bf16.h>
#include <stdint.h>

#define Bq  8
#define Sq  2048
#define Dq  768
#define Hq  3072
#define Oq  768
#define Eq  8
#define Mq  (Bq*Sq)            // 16384 tokens
#define LN_EPS 1e-5f
#define MAX_T256 (Mq/128 + 16)      // 144 worst-case padded 256-row tiles

typedef unsigned short u16;
typedef __attribute__((ext_vector_type(4))) float f32x4;
typedef __attribute__((ext_vector_type(8))) __bf16 bf16x8;

static __device__ __forceinline__ u16 f2bf(float f) {
  __hip_bfloat16 h = __float2bfloat16(f);
  return __builtin_bit_cast(u16, h);
}

static __device__ __forceinline__ float gelu_f(float x) {
  float u = 0.7978845608028654f * x * (1.0f + 0.044715f * x * x);
  float e = __expf(2.0f * u);
  float t = 1.0f - 2.0f / (e + 1.0f);   // tanh(u), NaN-free
  return 0.5f * x * (1.0f + t);
}

typedef const __attribute__((address_space(1))) void* gas_t;
typedef __attribute__((address_space(3))) void* las_t;
static __device__ __forceinline__ void gload16(const void* g, void* l) {
  __builtin_amdgcn_global_load_lds((gas_t)g, (las_t)l, 16, 0, 0);
}

// ---------------- fused router + fp32->bf16 convert. NO atomics.
__global__ __launch_bounds__(256) void router_cvt_kernel(
    const float* __restrict__ x, const float* __restrict__ rw,
    const float* __restrict__ rb, u16* __restrict__ Xbf,
    int* __restrict__ tok_seg, float2* __restrict__ tok_w)
{
  __shared__ float rwT[Eq * Dq];
  for (int i = threadIdx.x; i < Eq * Dq; i += 256)
    rwT[(i & 7) * Dq + (i >> 3)] = rw[i];
  __syncthreads();

  int wid = threadIdx.x >> 6;
  int lane = threadIdx.x & 63;
  int token = blockIdx.x * 4 + wid;
  const float4* xrow = (const float4*)(x + (size_t)token * Dq);
  ushort4* orow = (ushort4*)(Xbf + (size_t)token * Dq);

  float acc[Eq];
#pragma unroll
  for (int e = 0; e < Eq; e++) acc[e] = 0.f;

#pragma unroll
  for (int it = 0; it < Dq / 256; it++) {
    int d4 = it * 64 + lane;
    float4 xv = xrow[d4];
    ushort4 o;
    o.x = f2bf(xv.x); o.y = f2bf(xv.y); o.z = f2bf(xv.z); o.w = f2bf(xv.w);
    orow[d4] = o;
    int d = d4 * 4;
#pragma unroll
    for (int e = 0; e < Eq; e++) {
      float4 wv = *(const float4*)&rwT[e * Dq + d];
      acc[e] += xv.x * wv.x + xv.y * wv.y + xv.z * wv.z + xv.w * wv.w;
    }
  }
#pragma unroll
  for (int e = 0; e < Eq; e++) {
    float v = acc[e];
#pragma unroll
    for (int off = 32; off; off >>= 1) v += __shfl_xor(v, off);
    acc[e] = v;
  }
  if (lane == 0) {
    float v1 = -1e30f, v2 = -1e30f; int i1 = 0, i2 = 0;
#pragma unroll
    for (int e = 0; e < Eq; e++) {
      float v = acc[e] + rb[e];
      if (v > v1)      { v2 = v1; i2 = i1; v1 = v; i1 = e; }
      else if (v > v2) { v2 = v;  i2 = e; }
    }
    float ex = expf(v2 - v1);
    float wa = 1.f / (1.f + ex);
    float wb = ex / (1.f + ex);
    tok_seg[token] = i1 | ((8 + i2) << 8);
    tok_w[token] = make_float2(wa, wb);
  }
}

// ---------------- segment-list build, block-aggregated atomics.
__global__ __launch_bounds__(256) void scatter_build(
    const int* __restrict__ tok_seg, const float2* __restrict__ tok_w,
    int* __restrict__ cnt, int* __restrict__ seg_tok, float* __restrict__ seg_wgt)
{
  __shared__ int histA[16], histB[16], base[16];
  int t = threadIdx.x;
  if (t < 16) { histA[t] = 0; histB[t] = 0; }
  __syncthreads();
  int token = blockIdx.x * 256 + t;
  int sp = tok_seg[token];
  float2 wv = tok_w[token];
  int s0 = sp & 0xff, s1 = sp >> 8;
  atomicAdd(&histA[s0], 1);
  atomicAdd(&histA[s1], 1);
  __syncthreads();
  if (t < 16) base[t] = atomicAdd(&cnt[t], histA[t]);
  __syncthreads();
  int p0 = base[s0] + atomicAdd(&histB[s0], 1);
  seg_tok[(size_t)s0 * Mq + p0] = token;
  seg_wgt[(size_t)s0 * Mq + p0] = wv.x;
  int p1 = base[s1] + atomicAdd(&histB[s1], 1);
  seg_tok[(size_t)s1 * Mq + p1] = token;
  seg_wgt[(size_t)s1 * Mq + p1] = wv.y;
}

// ---------------- tile prefix over 16 segments, 256-row padding
__global__ void prefix_kernel(const int* __restrict__ cnt, int* __restrict__ prefix)
{
  if (threadIdx.x == 0 && blockIdx.x == 0) {
    int t = 0;
#pragma unroll
    for (int s = 0; s < 16; s++) { prefix[s] = t; t += (cnt[s] + 255) >> 8; }
    prefix[16] = t;
  }
}

// ---------------- transpose+convert: in[R][C] f32 -> out[C][R] bf16, per expert z
__global__ __launch_bounds__(256) void transpose_cvt(
    const float* __restrict__ in, u16* __restrict__ out, int R, int C)
{
  __shared__ float tile[32][33];
  int e = blockIdx.z;
  in  += (size_t)e * R * C;
  out += (size_t)e * R * C;
  int c0 = blockIdx.x * 32, r0 = blockIdx.y * 32;
  int tx = threadIdx.x & 31, ty = threadIdx.x >> 5;
#pragma unroll
  for (int rr = 0; rr < 32; rr += 8)
    tile[rr + ty][tx] = in[(size_t)(r0 + rr + ty) * C + c0 + tx];
  __syncthreads();
#pragma unroll
  for (int rr = 0; rr < 32; rr += 8)
    out[(size_t)(c0 + rr + ty) * R + r0 + tx] = f2bf(tile[tx][rr + ty]);
}

// ---------------- GEMM1: 256x256 tile, 8 waves (2Mx4N), BK=64, phase-
// pipelined K-loop; LDS 128KB flat smem: As(2x32KB) | Bs(2x32KB).
// After the K-loop, smem is DEAD and reused as a [256][256] bf16 out-tile
// so the Hout write is fully coalesced (16B/lane) instead of 2B scatters.
__global__ __launch_bounds__(512, 2) void moe_gemm1(
    const u16* __restrict__ A, const u16* __restrict__ W,
    const float* __restrict__ bias, u16* __restrict__ Hout,
    const int* __restrict__ cnt, const int* __restrict__ prefix,
    const int* __restrict__ seg_tok, int K, int N, int tile_lo)
{
  const int NP = N / 256;               // 12 panels
  const int lid = (int)blockIdx.x + NP * (int)blockIdx.y;
  const int xcd = lid & 7, slot = lid >> 3;
  const int t_loc = xcd + 8 * (slot / NP);   // gridDim.y multiple of 8
  const int panel = slot % NP;

  const int t = tile_lo + t_loc;
  if (t >= prefix[16]) return;
  int seg = 0;
#pragma unroll
  for (int s = 1; s < 16; s++) if (prefix[s] <= t) seg = s;
  const int e = seg & 7;
  const int segcnt = cnt[seg];
  const int ti = t - prefix[seg];
  const int lt = t_loc;

  __shared__ u16 smem[65536];           // 128 KB
  const int tid  = threadIdx.x;
  const int lane = tid & 63;
  const int wid  = tid >> 6;
  const int wr   = wid >> 2, wc = wid & 3;    // 2M x 4N waves
  const int lrow = lane & 15, kgrp = lane >> 4;
  const int gcx0 = ((kgrp)     ^ (lrow & 7)) * 8;
  const int gcx1 = ((4 + kgrp) ^ (lrow & 7)) * 8;

  f32x4 acc[8][4];
#pragma unroll
  for (int m = 0; m < 8; m++)
#pragma unroll
    for (int n = 0; n < 4; n++) acc[m][n] = (f32x4){0.f, 0.f, 0.f, 0.f};

  const int srow = tid >> 3;
  const int swz  = ((tid & 7) ^ (srow & 7)) * 8;
  const u16 *pA00, *pA01, *pA10, *pA11, *pB00, *pB01, *pB10, *pB11;
  {
    int sr;
    sr = ti * 256 +   0 +  0 + srow;
    pA00 = A + (size_t)((sr < segcnt) ? seg_tok[(size_t)seg * Mq + sr] : 0) * K + swz;
    sr = ti * 256 +   0 + 64 + srow;
    pA01 = A + (size_t)((sr < segcnt) ? seg_tok[(size_t)seg * Mq + sr] : 0) * K + swz;
    sr = ti * 256 + 128 +  0 + srow;
    pA10 = A + (size_t)((sr < segcnt) ? seg_tok[(size_t)seg * Mq + sr] : 0) * K + swz;
    sr = ti * 256 + 128 + 64 + srow;
    pA11 = A + (size_t)((sr < segcnt) ? seg_tok[(size_t)seg * Mq + sr] : 0) * K + swz;
    const u16* Wb = W + (size_t)e * K * N;
    pB00 = Wb + (size_t)(panel * 256 +   0 +  0 + srow) * K + swz;
    pB01 = Wb + (size_t)(panel * 256 +   0 + 64 + srow) * K + swz;
    pB10 = Wb + (size_t)(panel * 256 + 128 +  0 + srow) * K + swz;
    pB11 = Wb + (size_t)(panel * 256 + 128 + 64 + srow) * K + swz;
  }

  // As slot s at smem + s*16384; Bs slot s at smem + 32768 + s*16384
#define STG(base, h, P0, P1)                               \
  do {                                                     \
    gload16(P0, &smem[(base) + (h) * 8192 + tid * 8]);     \
    gload16(P1, &smem[(base) + (h) * 8192 + 4096 + tid * 8]); \
    P0 += 64; P1 += 64;                                    \
  } while (0)

  const int NKT = K / 64;               // 12 K-tiles
  STG(0, 0, pA00, pA01); STG(0, 1, pA10, pA11);
  STG(32768, 0, pB00, pB01); STG(32768, 1, pB10, pB11);

  bf16x8 bfr[4][2];
  for (int kt = 0; kt < NKT; ++kt) {
    const int s = kt & 1;
    const int sA = s * 16384, sB = 32768 + s * 16384;
    const int dA = (s ^ 1) * 16384, dB = 32768 + (s ^ 1) * 16384;
    const bool more = (kt + 1 < NKT);
    const int abase = wr * 128 + lrow;
    const int bbase = wc * 64 + lrow;

    // ---- phase 0
    if (more) {
      STG(dA, 0, pA00, pA01);
      asm volatile("s_waitcnt vmcnt(2)" ::: "memory");
    } else {
      asm volatile("s_waitcnt vmcnt(0)" ::: "memory");
    }
    __builtin_amdgcn_s_barrier();
    __builtin_amdgcn_sched_barrier(0);
#pragma unroll
    for (int n = 0; n < 4; n++) {
      bfr[n][0] = *(const bf16x8*)&smem[sB + (bbase + n * 16) * 64 + gcx0];
      bfr[n][1] = *(const bf16x8*)&smem[sB + (bbase + n * 16) * 64 + gcx1];
    }
    {
      bf16x8 a00 = *(const bf16x8*)&smem[sA + (abase +  0) * 64 + gcx0];
      bf16x8 a01 = *(const bf16x8*)&smem[sA + (abase +  0) * 64 + gcx1];
      bf16x8 a10 = *(const bf16x8*)&smem[sA + (abase + 16) * 64 + gcx0];
      bf16x8 a11 = *(const bf16x8*)&smem[sA + (abase + 16) * 64 + gcx1];
      __builtin_amdgcn_s_setprio(1);
#pragma unroll
      for (int n = 0; n < 4; n++) {
        acc[0][n] = __builtin_amdgcn_mfma_f32_16x16x32_bf16(a00, bfr[n][0], acc[0][n], 0, 0, 0);
        acc[0][n] = __builtin_amdgcn_mfma_f32_16x16x32_bf16(a01, bfr[n][1], acc[0][n], 0, 0, 0);
        acc[1][n] = __builtin_amdgcn_mfma_f32_16x16x32_bf16(a10, bfr[n][0], acc[1][n], 0, 0, 0);
        acc[1][n] = __builtin_amdgcn_mfma_f32_16x16x32_bf16(a11, bfr[n][1], acc[1][n], 0, 0, 0);
      }
      __builtin_amdgcn_s_setprio(0);
    }
    __builtin_amdgcn_sched_barrier(0);
    __builtin_amdgcn_s_barrier();

#define PHASE(q, STGSTMT)                                                     \
    do {                                                                      \
      bf16x8 a00 = *(const bf16x8*)&smem[sA + (abase + (2*(q))    * 16) * 64 + gcx0]; \
      bf16x8 a01 = *(const bf16x8*)&smem[sA + (abase + (2*(q))    * 16) * 64 + gcx1]; \
      bf16x8 a10 = *(const bf16x8*)&smem[sA + (abase + (2*(q)+1)  * 16) * 64 + gcx0]; \
      bf16x8 a11 = *(const bf16x8*)&smem[sA + (abase + (2*(q)+1)  * 16) * 64 + gcx1]; \
      if (more) { STGSTMT; }                                                  \
      __builtin_amdgcn_s_setprio(1);                                          \
      _Pragma("unroll")                                                       \
      for (int n = 0; n < 4; n++) {                                           \
        acc[2*(q)][n]   = __builtin_amdgcn_mfma_f32_16x16x32_bf16(a00, bfr[n][0], acc[2*(q)][n], 0, 0, 0);   \
        acc[2*(q)][n]   = __builtin_amdgcn_mfma_f32_16x16x32_bf16(a01, bfr[n][1], acc[2*(q)][n], 0, 0, 0);   \
        acc[2*(q)+1][n] = __builtin_amdgcn_mfma_f32_16x16x32_bf16(a10, bfr[n][0], acc[2*(q)+1][n], 0, 0, 0); \
        acc[2*(q)+1][n] = __builtin_amdgcn_mfma_f32_16x16x32_bf16(a11, bfr[n][1], acc[2*(q)+1][n], 0, 0, 0); \
      }                                                                       \
      __builtin_amdgcn_s_setprio(0);                                          \
      __builtin_amdgcn_sched_barrier(0);                                      \
      __builtin_amdgcn_s_barrier();                                           \
    } while (0)

    PHASE(1, STG(dA, 1, pA10, pA11));
    PHASE(2, STG(dB, 0, pB00, pB01));
    PHASE(3, STG(dB, 1, pB10, pB11));
#undef PHASE
  }
#undef STG

  // ---- epilogue: scatter acc -> smem[256][256] bf16, then coalesced store
  {
    const int rb = wr * 128, cb = wc * 64;
#pragma unroll
    for (int n = 0; n < 4; n++) {
      int cc = cb + n * 16 + lrow;
      float bv = bias[(size_t)e * N + panel * 256 + cc];
#pragma unroll
      for (int m = 0; m < 8; m++)
#pragma unroll
        for (int j = 0; j < 4; j++) {
          int rr = rb + m * 16 + kgrp * 4 + j;
          smem[rr * 256 + cc] = f2bf(gelu_f(acc[m][n][j] + bv));
        }
    }
    __syncthreads();
    const int r = tid >> 5, c8 = (tid & 31) * 8;
    u16* gdst = Hout + (size_t)(lt * 256) * N + (size_t)panel * 256;
#pragma unroll
    for (int it2 = 0; it2 < 16; ++it2) {
      int rr = it2 * 16 + r;
      *(uint4*)(gdst + (size_t)rr * N + c8) = *(const uint4*)&smem[rr * 256 + c8];
    }
  }
}

// ---------------- GEMM2: proven 128x128 4-wave 2-deep dbuf structure,
// mapped onto 256-padded tiles as 128-sub-tiles.
__global__ __launch_bounds__(256) void moe_gemm2(
    const u16* __restrict__ A, const u16* __restrict__ W,
    const float* __restrict__ bias, float* __restrict__ out,
    const int* __restrict__ cnt, const int* __restrict__ prefix,
    const int* __restrict__ seg_tok, const float* __restrict__ seg_wgt,
    int K, int N, int tile_lo)
{
  const int NP = N / 128;               // 6 panels
  const int lid = (int)blockIdx.x + NP * (int)blockIdx.y;
  const int xcd = lid & 7, slot = lid >> 3;
  const int t2 = xcd + 8 * (slot / NP);
  const int panel = slot % NP;

  const int t256 = tile_lo + (t2 >> 1);
  if (t256 >= prefix[16]) return;
  int seg = 0;
#pragma unroll
  for (int s = 1; s < 16; s++) if (prefix[s] <= t256) seg = s;
  const int e = seg & 7;
  const int segcnt = cnt[seg];
  const int ti = (t256 - prefix[seg]) * 2 + (t2 & 1);
  const int lt = t2;

  __shared__ u16 As[2][128 * 32];
  __shared__ u16 Bs[2][128 * 32];
  const int tid  = threadIdx.x;
  const int lane = tid & 63;
  const int wid  = tid >> 6;
  const int wr   = wid >> 1, wc = wid & 1;
  const int lrow = lane & 15, kgrp = lane >> 4;
  const int kx   = kgrp ^ ((lrow >> 1) & 3);
  const int n0 = panel * 128;

  f32x4 acc[4][4];
#pragma unroll
  for (int m = 0; m < 4; m++)
#pragma unroll
    for (int n = 0; n < 4; n++) acc[m][n] = (f32x4){0.f, 0.f, 0.f, 0.f};

  const int r0 = tid >> 2;
  const int kc = (((tid & 3) ^ ((tid >> 3) & 3)) * 8);
  const u16* gA0 = A + (size_t)(lt * 128 + r0) * K + kc;
  const u16* gA1 = gA0 + (size_t)64 * K;
  const u16* gB = W + (size_t)e * K * N + (size_t)(n0 + r0) * K + kc;
  const size_t rowskipB = (size_t)64 * K;
  const int lofs = tid * 8;

  auto stage = [&](int b) {
    gload16(gA0, &As[b][lofs]);
    gload16(gA1, &As[b][lofs + 2048]);
    gload16(gB,            &Bs[b][lofs]);
    gload16(gB + rowskipB, &Bs[b][lofs + 2048]);
    gA0 += 32; gA1 += 32; gB += 32;
  };

  const int NIT = K / 32;
  stage(0);
  for (int it = 0; it < NIT; ++it) {
    const int cur = it & 1;
    if (it + 1 < NIT) {
      stage(cur ^ 1);
      asm volatile("s_waitcnt vmcnt(4)" ::: "memory");
    } else {
      asm volatile("s_waitcnt vmcnt(0)" ::: "memory");
    }
    __builtin_amdgcn_s_barrier();
    __builtin_amdgcn_sched_barrier(0);
    bf16x8 a[4], b[4];
#pragma unroll
    for (int m = 0; m < 4; m++)
      a[m] = *(const bf16x8*)&As[cur][(wr * 64 + m * 16 + lrow) * 32 + kx * 8];
#pragma unroll
    for (int n = 0; n < 4; n++)
      b[n] = *(const bf16x8*)&Bs[cur][(wc * 64 + n * 16 + lrow) * 32 + kx * 8];
#pragma unroll
    for (int m = 0; m < 4; m++)
#pragma unroll
      for (int n = 0; n < 4; n++)
        acc[m][n] = __builtin_amdgcn_mfma_f32_16x16x32_bf16(a[m], b[n], acc[m][n], 0, 0, 0);
    __builtin_amdgcn_sched_barrier(0);
    __builtin_amdgcn_s_barrier();
  }

  const int rbase = wr * 64;
  const int cbase = n0 + wc * 64;
#pragma unroll
  for (int m = 0; m < 4; m++)
#pragma unroll
    for (int j = 0; j < 4; j++) {
      int r = rbase + m * 16 + kgrp * 4 + j;
      int i = ti * 128 + r;
      if (i < segcnt) {
        int token = seg_tok[(size_t)seg * Mq + i];
        float w = seg_wgt[(size_t)seg * Mq + i];
        float* orow = out + (size_t)token * Oq;
#pragma unroll
        for (int n = 0; n < 4; n++) {
          int c = cbase + n * 16 + lrow;
          float v = (acc[m][n][j] + bias[(size_t)e * N + c]) * w;
          unsafeAtomicAdd(&orow[c], v);
        }
      }
    }
}

// ---------------- in-place LayerNorm, one wave per row
__global__ __launch_bounds__(256) void ln_kernel(
    float* __restrict__ io, const float* __restrict__ g, const float* __restrict__ b)
{
  int wid = threadIdx.x >> 6, lane = threadIdx.x & 63;
  int row = blockIdx.x * 4 + wid;
  float* p = io + (size_t)row * Oq;
  float v[Oq / 64];
  float s = 0.f;
#pragma unroll
  for (int i = 0; i < Oq / 64; i++) { v[i] = p[lane + i * 64]; s += v[i]; }
#pragma unroll
  for (int off = 32; off; off >>= 1) s += __shfl_xor(s, off);
  float mu = s * (1.0f / Oq);
  float q = 0.f;
#pragma unroll
  for (int i = 0; i < Oq / 64; i++) { float d = v[i] - mu; q += d * d; }
#pragma unroll
  for (int off = 32; off; off >>= 1) q += __shfl_xor(q, off);
  float inv = rsqrtf(q * (1.0f / Oq) + LN_EPS);
#pragma unroll
  for (int i = 0; i < Oq / 64; i++) {
    int c = lane + i * 64;
    p[c] = (v[i] - mu) * inv * g[c] + b[c];
  }
}

extern "C" void kernel_launch(void* const* d_in, const int* in_sizes, int n_in,
                              void* d_out, int out_size, void* d_ws, size_t ws_size,
                              hipStream_t stream)
{
  const float* x    = (const float*)d_in[0];
  const float* rw   = (const float*)d_in[1];
  const float* rb   = (const float*)d_in[2];
  const float* w1   = (const float*)d_in[3];
  const float* b1   = (const float*)d_in[4];
  const float* w2   = (const float*)d_in[5];
  const float* b2   = (const float*)d_in[6];
  const float* ln_g = (const float*)d_in[7];
  const float* ln_b = (const float*)d_in[8];
  float* out = (float*)d_out;

  char* ws = (char*)d_ws;
  size_t off = 0;
  auto alloc = [&](size_t bytes) {
    void* p = ws + off;
    off += (bytes + 255) & ~(size_t)255;
    return p;
  };
  int*    cnt     = (int*)alloc(16 * 4);
  int*    prefix  = (int*)alloc(17 * 4);
  int*    tok_seg = (int*)alloc((size_t)Mq * 4);
  float2* tok_w   = (float2*)alloc((size_t)Mq * 8);
  int*    seg_tok = (int*)alloc((size_t)16 * Mq * 4);
  float*  seg_wgt = (float*)alloc((size_t)16 * Mq * 4);
  u16* Xbf = (u16*)alloc((size_t)Mq * Dq * 2);
  u16* W1T = (u16*)alloc((size_t)Eq * Dq * Hq * 2);
  u16* W2T = (u16*)alloc((size_t)Eq * Hq * Oq * 2);

  size_t remain = (ws_size > off) ? ws_size - off : 0;
  size_t tile_bytes = (size_t)256 * Hq * 2;   // 1.5 MB per 256-row tile
  long long wt = (long long)(remain / tile_bytes);
  if (wt > MAX_T256) wt = MAX_T256;
  wt &= ~7LL;                 // multiple of 8 for the XCD remap bijection
  if (wt < 8) wt = 8;
  int WT = (int)wt;
  u16* Hbuf = (u16*)alloc((size_t)WT * tile_bytes);

  hipMemsetAsync(out, 0, (size_t)Mq * Oq * 4, stream);
  hipMemsetAsync(cnt, 0, 16 * 4, stream);
  router_cvt_kernel<<<Mq / 4, 256, 0, stream>>>(x, rw, rb, Xbf, tok_seg, tok_w);
  scatter_build<<<Mq / 256, 256, 0, stream>>>(tok_seg, tok_w, cnt, seg_tok, seg_wgt);
  prefix_kernel<<<1, 64, 0, stream>>>(cnt, prefix);
  transpose_cvt<<<dim3(Hq / 32, Dq / 32, Eq), 256, 0, stream>>>(w1, W1T, Dq, Hq);
  transpose_cvt<<<dim3(Oq / 32, Hq / 32, Eq), 256, 0, stream>>>(w2, W2T, Hq, Oq);

  for (int tl = 0; tl < MAX_T256; tl += WT) {
    int gx = MAX_T256 - tl; if (gx > WT) gx = WT;   // stays multiple of 8
    moe_gemm1<<<dim3(Hq / 256, gx), 512, 0, stream>>>(
        Xbf, W1T, b1, Hbuf, cnt, prefix, seg_tok, Dq, Hq, tl);
    moe_gemm2<<<dim3(Oq / 128, 2 * gx), 256, 0, stream>>>(
        Hbuf, W2T, b2, out, cnt, prefix, seg_tok, seg_wgt, Hq, Oq, tl);
  }
  ln_kernel<<<Mq / 4, 256, 0, stream>>>(out, ln_g, ln_b);
}